// Round 16
// baseline (242.108 us; speedup 1.0000x reference)
//
#include <hip/hip_runtime.h>

#define HID 128
#define NF 13
#define SLEN 128
#define NSEQ 2048
#define SEQS 8            // seqs per WG
#define ZSTRIDE 236       // f16/row: 118 bank-words, gcd(22,32)=2 -> 2-way max
#define LOG2E 1.44269504088896340736f

typedef _Float16 half8 __attribute__((ext_vector_type(8)));
typedef float floatx4 __attribute__((ext_vector_type(4)));

__device__ __forceinline__ float fast_rcp(float x) { return __builtin_amdgcn_rcpf(x); }
__device__ __forceinline__ float fast_ex2(float x) { return __builtin_amdgcn_exp2f(x); }
// gate pre-scaled by log2(e):  sigmoid(raw) = 1/(1+2^-x)
__device__ __forceinline__ float sigm2(float x)  { return fast_rcp(1.0f + fast_ex2(-x)); }
// gate pre-scaled by 2*log2(e): tanh(raw) = 1 - 2/(1+2^x)
__device__ __forceinline__ float tanh2(float x)  { return 1.0f - 2.0f * fast_rcp(1.0f + fast_ex2(x)); }

// Light barrier (r15, neutral but harmless): lgkmcnt-only drain before s_barrier.
#define LIGHT_SYNC()                                                           \
    do {                                                                       \
        asm volatile("s_waitcnt lgkmcnt(0)\n\ts_barrier" ::: "memory");        \
        __builtin_amdgcn_sched_barrier(0);                                     \
    } while (0)

// ---- precompute: W_eff = (W_hh + W_ih @ W_fc) * gate_scale (f16),
//                  b_eff = (b_ih+b_hh+W_ih@b_fc) * gate_scale (f32)
__global__ __launch_bounds__(256)
void weff_kernel(const float* __restrict__ W_ih, const float* __restrict__ W_hh,
                 const float* __restrict__ b_ih, const float* __restrict__ b_hh,
                 const float* __restrict__ W_fc, const float* __restrict__ b_fc,
                 _Float16* __restrict__ w_eff, float* __restrict__ b_eff)
{
    const int idx = blockIdx.x * 256 + threadIdx.x;   // 4H*H = 65536 total
    const int n = idx >> 7, k = idx & 127;
    const float sg = ((n >> 7) == 2) ? 2.0f * LOG2E : LOG2E;
    float s = W_hh[n * HID + k];
    #pragma unroll
    for (int f = 0; f < NF; ++f) s += W_ih[n * NF + f] * W_fc[f * HID + k];
    w_eff[n * HID + k] = (_Float16)(s * sg);
    if (k == 0) {
        float bb = b_ih[n] + b_hh[n];
        #pragma unroll
        for (int f = 0; f < NF; ++f) bb += W_ih[n * NF + f] * b_fc[f];
        b_eff[n] = bb * sg;
    }
}

// r15 structure (best: ~190us main, latency/phase-bound: MFMA 34% / VALU 39%
// serialized by lockstep waves). This round: STATIC ASYMMETRIC WAVE PRIORITY —
// odd waves get s_setprio(1) once. Within each inter-barrier interval the
// prio-1 wave wins issue slots, clears its MFMA cluster at dep-chain speed and
// runs its VALU epilogue while the prio-0 wave still feeds the matrix pipe:
// intra-interval de-phasing without touching the (fragile) barrier structure.
__global__ __launch_bounds__(512, 1)
void lstm_encdec_kernel(const float* __restrict__ X,
                        const float* __restrict__ W_ih,
                        const float* __restrict__ W_hh,
                        const float* __restrict__ b_ih,
                        const float* __restrict__ b_hh,
                        const float* __restrict__ W_fc,
                        const float* __restrict__ b_fc,
                        const _Float16* __restrict__ w_eff,
                        const float* __restrict__ b_eff,
                        float* __restrict__ out)
{
    // z = [h(128)|x(13 pad)] per seq at row 2s; double-buffered, static indices.
    __shared__ _Float16 zbuf[2][16 * ZSTRIDE];      // 15104 B
    __shared__ half8 wfcl[256];                     // [ks][lane] W_fc frags, 4 KB

    const int tid  = threadIdx.x;
    const int gw   = tid >> 6;            // wave 0..7 == unit-group
    const int lane = tid & 63;
    const int quad = lane >> 4;           // 0..3
    const int lcol = lane & 15;
    const int u    = gw * 16 + lcol;      // hidden unit 0..127
    const int seq0 = blockIdx.x * SEQS;

    // ---- per-wave B fragments: all 4 gates x (4 h K-steps + 1 x K-step) ----
    half8 Bf[4][5];
    floatx4 biasv[4];
    #pragma unroll
    for (int g2 = 0; g2 < 4; ++g2) {
        const int n = g2 * HID + u;
        const float sg = (g2 == 2) ? 2.0f * LOG2E : LOG2E;
        #pragma unroll
        for (int ks = 0; ks < 4; ++ks) {
            const float* pw = W_hh + n * HID + ks * 32 + quad * 8;
            half8 v;
            #pragma unroll
            for (int j = 0; j < 8; ++j) v[j] = (_Float16)(pw[j] * sg);
            Bf[g2][ks] = v;
        }
        {   // x part (K-step 4), kept in registers (loop-invariant per wave)
            half8 v;
            #pragma unroll
            for (int j = 0; j < 8; ++j) {
                const int kk = quad * 8 + j;
                v[j] = (kk < NF) ? (_Float16)(W_ih[n * NF + kk] * sg) : (_Float16)0.0f;
            }
            Bf[g2][4] = v;
        }
        const float b = (b_ih[n] + b_hh[n]) * sg;
        biasv[g2] = (floatx4){b, b, b, b};
    }
    const float bfc = (lcol < NF) ? b_fc[lcol] : 0.0f;

    // ---- stage W_fc fragments: entry (ks,lane), 256 x 16B ----
    if (tid < 256) {
        const int lane_i = tid & 63, ks_i = tid >> 6;
        const int quad_i = lane_i >> 4, lcol_i = lane_i & 15;
        half8 v;
        #pragma unroll
        for (int j = 0; j < 8; ++j)
            v[j] = (lcol_i < NF)
                 ? (_Float16)W_fc[lcol_i * HID + ks_i * 32 + quad_i * 8 + j]
                 : (_Float16)0.0f;
        wfcl[tid] = v;
    }

    // ---- zero both z bufs (odd rows + x pads stay zero), then x_0 ----
    for (int i = tid; i < 2 * 16 * ZSTRIDE; i += 512)
        ((_Float16*)zbuf)[i] = (_Float16)0.0f;
    __syncthreads();
    const bool xact = tid < SEQS * NF;                // 104 loader threads
    const int  xs = tid / NF, xf = tid % NF;
    const long xbase = (long)(seq0 + xs) * SLEN * NF + xf;
    if (xact) zbuf[0][(2 * xs) * ZSTRIDE + HID + xf] = (_Float16)X[xbase];
    __syncthreads();

    // static asymmetric priority: odd waves lead within each barrier interval
    if (gw & 1) __builtin_amdgcn_s_setprio(1);

    float creg0 = 0.0f, creg1 = 0.0f, h0 = 0.0f, h1 = 0.0f;

    // GATES_CORE(P,WX): a[] from zbuf[P] (static), 16 (or 20 with x) MFMA
#define GATES_CORE(P, WX)                                                      \
    half8 a[5];                                                                \
    _Pragma("unroll")                                                          \
    for (int ks = 0; ks < 4; ++ks)                                             \
        a[ks] = *(const half8*)&zbuf[P][lcol * ZSTRIDE + ks * 32 + quad * 8];  \
    floatx4 acc[4];                                                            \
    _Pragma("unroll")                                                          \
    for (int g2 = 0; g2 < 4; ++g2)                                             \
        acc[g2] = __builtin_amdgcn_mfma_f32_16x16x32_f16(a[0], Bf[g2][0], biasv[g2], 0, 0, 0); \
    _Pragma("unroll")                                                          \
    for (int ks = 1; ks < 4; ++ks)                                             \
        _Pragma("unroll")                                                      \
        for (int g2 = 0; g2 < 4; ++g2)                                         \
            acc[g2] = __builtin_amdgcn_mfma_f32_16x16x32_f16(a[ks], Bf[g2][ks], acc[g2], 0, 0, 0); \
    if (WX) {                                                                  \
        a[4] = *(const half8*)&zbuf[P][lcol * ZSTRIDE + HID + quad * 8];       \
        _Pragma("unroll")                                                      \
        for (int g2 = 0; g2 < 4; ++g2)                                         \
            acc[g2] = __builtin_amdgcn_mfma_f32_16x16x32_f16(a[4], Bf[g2][4], acc[g2], 0, 0, 0); \
    }

    // in-register epilogue: 2 cells/thread (seqs 2q, 2q+1; unit u) -> zbuf[WP]
#define EPI_BODY(WP)                                                           \
    {                                                                          \
        float c0 = sigm2(acc[1][0]) * creg0 + sigm2(acc[0][0]) * tanh2(acc[2][0]); \
        creg0 = c0;                                                            \
        h0 = sigm2(acc[3][0]) * tanh2(c0 * (2.0f * LOG2E));                    \
        float c1 = sigm2(acc[1][2]) * creg1 + sigm2(acc[0][2]) * tanh2(acc[2][2]); \
        creg1 = c1;                                                            \
        h1 = sigm2(acc[3][2]) * tanh2(c1 * (2.0f * LOG2E));                    \
        zbuf[WP][(4 * quad) * ZSTRIDE + u]     = (_Float16)h0;                 \
        zbuf[WP][(4 * quad + 2) * ZSTRIDE + u] = (_Float16)h1;                 \
    }

    // encoder step: read buf RP, write buf WP; x-write before EPI (off the tail)
#define ESTEP(RP, WP, TT)                                                      \
    {                                                                          \
        const int tn = ((TT) + 1 < SLEN) ? (TT) + 1 : SLEN - 1;                \
        float xpre = xact ? X[xbase + tn * NF] : 0.0f;                         \
        GATES_CORE(RP, 1)                                                      \
        if (xact) zbuf[WP][(2 * xs) * ZSTRIDE + HID + xf] = (_Float16)xpre;    \
        EPI_BODY(WP)                                                           \
        LIGHT_SYNC();                                                          \
    }

    // ============ encoder: 128 steps, 2-step unrolled, 1 light barrier/step ======
    for (int t = 0; t < SLEN; t += 2) {
        ESTEP(0, 1, t)
        ESTEP(1, 0, t + 1)
    }

    // embeddings = h_n
    out[(long)(seq0 + 2 * quad) * HID + u]     = h0;
    out[(long)(seq0 + 2 * quad + 1) * HID + u] = h1;

    float* dec = out + (long)NSEQ * HID;

    // ============ decoder step 0: real x_127 (5 K-steps, original weights) ========
    {
        GATES_CORE(0, 1)
        EPI_BODY(1)
        LIGHT_SYNC();
    }

    // ---- swap to folded effective weights (16 dwordx4 loads) ----
    #pragma unroll
    for (int g2 = 0; g2 < 4; ++g2) {
        const int n = g2 * HID + u;
        #pragma unroll
        for (int ks = 0; ks < 4; ++ks)
            Bf[g2][ks] = *(const half8*)&w_eff[n * HID + ks * 32 + quad * 8];
        const float b = b_eff[n];
        biasv[g2] = (floatx4){b, b, b, b};
    }

    // decoder step: FC round-robin (all waves hold identical a[]; wfcl is shared)
#define DSTEP(RP, WP, TT)                                                      \
    {                                                                          \
        GATES_CORE(RP, 0)                                                      \
        if (gw == (((TT) - 1) & 7)) {      /* dec[TT-1] = FC(h_TT), reuses a[] */ \
            floatx4 o = (floatx4){bfc, bfc, bfc, bfc};                         \
            _Pragma("unroll")                                                  \
            for (int ks = 0; ks < 4; ++ks)                                     \
                o = __builtin_amdgcn_mfma_f32_16x16x32_f16(a[ks], wfcl[ks * 64 + lane], o, 0, 0, 0); \
            if (lcol < NF) {                                                   \
                dec[(long)(seq0 + 2 * quad) * SLEN * NF + ((TT) - 1) * NF + lcol]     = o[0]; \
                dec[(long)(seq0 + 2 * quad + 1) * SLEN * NF + ((TT) - 1) * NF + lcol] = o[2]; \
            }                                                                  \
        }                                                                      \
        EPI_BODY(WP)                                                           \
        LIGHT_SYNC();                                                          \
    }

    // ====== decoder steps 1..127: 4 K-steps, 1 light barrier, unrolled pairs =====
    DSTEP(1, 0, 1)
    for (int t = 2; t < SLEN; t += 2) {
        DSTEP(0, 1, t)
        DSTEP(1, 0, t + 1)
    }
    // final h (after t=127, second of pair) is in buf 0

    // ---- final dec output: dec[127] = FC(h_128) ----
    if (gw == 7) {
        half8 af[4];
        #pragma unroll
        for (int ks = 0; ks < 4; ++ks)
            af[ks] = *(const half8*)&zbuf[0][lcol * ZSTRIDE + ks * 32 + quad * 8];
        floatx4 o = (floatx4){bfc, bfc, bfc, bfc};
        #pragma unroll
        for (int ks = 0; ks < 4; ++ks)
            o = __builtin_amdgcn_mfma_f32_16x16x32_f16(af[ks], wfcl[ks * 64 + lane], o, 0, 0, 0);
        if (lcol < NF) {
            dec[(long)(seq0 + 2 * quad) * SLEN * NF + (SLEN - 1) * NF + lcol]     = o[0];
            dec[(long)(seq0 + 2 * quad + 1) * SLEN * NF + (SLEN - 1) * NF + lcol] = o[2];
        }
    }
}

extern "C" void kernel_launch(void* const* d_in, const int* in_sizes, int n_in,
                              void* d_out, int out_size, void* d_ws, size_t ws_size,
                              hipStream_t stream) {
    const float* X    = (const float*)d_in[0];
    const float* W_ih = (const float*)d_in[1];
    const float* W_hh = (const float*)d_in[2];
    const float* b_ih = (const float*)d_in[3];
    const float* b_hh = (const float*)d_in[4];
    const float* W_fc = (const float*)d_in[5];
    const float* b_fc = (const float*)d_in[6];
    float* out = (float*)d_out;

    _Float16* w_eff = (_Float16*)d_ws;                         // 4H*H f16 = 128 KiB
    float*    b_eff = (float*)((char*)d_ws + 4 * HID * HID * sizeof(_Float16));

    weff_kernel<<<(4 * HID * HID) / 256, 256, 0, stream>>>(
        W_ih, W_hh, b_ih, b_hh, W_fc, b_fc, w_eff, b_eff);

    lstm_encdec_kernel<<<NSEQ / SEQS, 512, 0, stream>>>(
        X, W_ih, W_hh, b_ih, b_hh, W_fc, b_fc, w_eff, b_eff, out);
}